// Round 10
// baseline (3363.585 us; speedup 1.0000x reference)
//
#include <hip/hip_runtime.h>
#include <hip/hip_fp16.h>

// GCN 3-layer encoder for MI355X — R10: SINGLE PERSISTENT MEGA-KERNEL.
// Evidence: k_agg is at a ~23cyc/edge floor (R6/R8/R9 nulls: invariant to
// bytes, lines, instr count); ~270us of the 427us total lives in 7 small
// never-profiled dispatches + launch gaps (R6 measured ~25us per added
// dispatch). So: fuse ALL 10 dispatches into one kernel with device-scope
// grid barriers. 2048 blocks x 256thr = exactly 8 blocks/CU
// (__launch_bounds__(256,8) forces VGPR<=64; LDS 16KB x 8 = 128KB <= 160).
// Phases (grid-stride, math byte-identical to R9):
//   P0 pre (zero tail, transpose W -> wt f16)
//   P1 bin  (512 active blocks, LDS histogram, 2-pass chunk scan)
//   P2 fill (block per 64-node partition: LDS slot counters, EW, cnt, dinv)
//   P3/5/7 gemm (MFMA, 16row x 64col wave tiles, NT=4 for VGPR<=64)
//   P4/6/8 agg  (R9 packed gather: 4 edges/instr @128 cols, 8 @64)
// Barriers: two-level (64 groups x 32 blocks), agent-scope acq/rel (G16).
// Packed-word shifts all on unsigned (R7: readlane/shfl return SIGNED).

typedef __attribute__((ext_vector_type(8))) _Float16 f16x8;
typedef __attribute__((ext_vector_type(4))) float f32x4;
typedef unsigned long long u64;

#define WQ_BITS 15
#define WQ_SCALE 32768.0f
#define WQ_MASK 32767u
#define MAXNP 2048
#define NBLK 2048
#define BINB 512

#define SHFLU(v, k) ((unsigned int)__shfl((int)(v), (k), 64))

__shared__ unsigned int sh_h[MAXNP];   // bin: histogram | fill: slot counters
__shared__ int sh_base[MAXNP];         // bin: bases     | fill: f32 weight sums

// Two-level grid barrier: 64 groups x 32 blocks. gcnt entries stride 32 u32
// (128B) to avoid line sharing. Agent scope = coherent across XCDs.
__device__ __forceinline__ void gbar(unsigned int* gcnt, unsigned int* root,
                                     unsigned int* gen) {
    __syncthreads();
    if (threadIdx.x == 0) {
        const int grp = (int)(blockIdx.x >> 5);  // requires gridDim.x == 2048
        unsigned int my = __hip_atomic_load(gen, __ATOMIC_ACQUIRE,
                                            __HIP_MEMORY_SCOPE_AGENT);
        unsigned int a = __hip_atomic_fetch_add(&gcnt[grp * 32], 1u,
                                                __ATOMIC_ACQ_REL,
                                                __HIP_MEMORY_SCOPE_AGENT);
        bool done = false;
        if (a == 31u) {
            unsigned int r = __hip_atomic_fetch_add(root, 1u, __ATOMIC_ACQ_REL,
                                                    __HIP_MEMORY_SCOPE_AGENT);
            if (r == 63u) {
                __hip_atomic_store(root, 0u, __ATOMIC_RELAXED,
                                   __HIP_MEMORY_SCOPE_AGENT);
                for (int i = 0; i < 64; i++)
                    __hip_atomic_store(&gcnt[i * 32], 0u, __ATOMIC_RELAXED,
                                       __HIP_MEMORY_SCOPE_AGENT);
                __hip_atomic_store(gen, my + 1u, __ATOMIC_RELEASE,
                                   __HIP_MEMORY_SCOPE_AGENT);
                done = true;
            }
        }
        if (!done)
            while (__hip_atomic_load(gen, __ATOMIC_ACQUIRE,
                                     __HIP_MEMORY_SCOPE_AGENT) == my)
                __builtin_amdgcn_s_sleep(2);
    }
    __syncthreads();
}

// ---- P0: zero tail + transpose W0/W1/W2 (fp32 [k][n]) -> f16 Wt [n][k] ----
__device__ __forceinline__ void pre_phase(int* tail, int NP,
                                          const float* __restrict__ W0,
                                          const float* __restrict__ W1,
                                          const float* __restrict__ W2,
                                          __half* __restrict__ wt0,
                                          __half* __restrict__ wt1,
                                          __half* __restrict__ wt2) {
    int preN = (NP > 40960) ? NP : 40960;
    for (int id = blockIdx.x * 256 + threadIdx.x; id < preN; id += NBLK * 256) {
        if (id < NP) tail[id] = 0;
        if (id < 16384) {
            int n = id >> 7, k = id & 127;
            wt0[id] = __float2half(W0[k * 128 + n]);
        } else if (id < 32768) {
            int j = id - 16384, n = j >> 7, k = j & 127;
            wt1[j] = __float2half(W1[k * 128 + n]);
        } else if (id < 40960) {
            int j = id - 32768, n = j >> 7, k = j & 127;  // n in [0,64)
            wt2[j] = __float2half(W2[k * 64 + n]);
        }
    }
}

// ---- P1: bin edges into NP per-node-range lists (blocks 0..BINB-1) ----
__device__ __forceinline__ void bin_phase(const int* __restrict__ src,
                                          const int* __restrict__ dst,
                                          const float* __restrict__ w,
                                          int* tail, u64* __restrict__ glist,
                                          int E, int ecap, int NP, int shift) {
    if (blockIdx.x >= BINB) return;  // inactive blocks fall to barrier
    const int per = (E + BINB - 1) / BINB;
    const int e0 = blockIdx.x * per;
    const int e1 = (e0 + per < E) ? e0 + per : E;

    for (int i = threadIdx.x; i < NP; i += 256) sh_h[i] = 0;
    __syncthreads();
    for (int e = e0 + (int)threadIdx.x; e < e1; e += 256) {
        int p = dst[e] >> shift;
        atomicAdd(&sh_h[p], 1u);
    }
    __syncthreads();
    for (int i = threadIdx.x; i < NP; i += 256) {
        unsigned int c = sh_h[i];
        sh_base[i] = c ? atomicAdd(&tail[i], (int)c) : 0;
    }
    __syncthreads();
    for (int e = e0 + (int)threadIdx.x; e < e1; e += 256) {
        int t = dst[e];  // L2-hot (pass 1 cached it)
        int p = t >> shift;
        int s = __builtin_nontemporal_load(src + e);
        float we = __builtin_nontemporal_load(w + e);
        int wq = (int)(we * WQ_SCALE + 0.5f);
        wq = (wq < (int)WQ_MASK) ? wq : (int)WQ_MASK;
        u64 v = ((u64)(unsigned)t << 32) |
                ((unsigned)s << WQ_BITS) | (unsigned)wq;
        unsigned int idx = atomicSub(&sh_h[p], 1u) - 1u;  // LDS, order-free
        int pos = sh_base[p] + (int)idx;
        if (pos < ecap) glist[(size_t)p * ecap + pos] = v;
    }
}

// ---- P2: per-partition scatter; LDS slot counters; emits EW, cnt, dinv ----
__device__ __forceinline__ void fill_phase(const int* __restrict__ tail,
                                           const u64* __restrict__ glist,
                                           int ecap, int* __restrict__ cnt,
                                           float* __restrict__ dinv,
                                           unsigned int* __restrict__ EW,
                                           int cap, int N, int NP, int shift) {
    const int np = 1 << shift;
    float* lws = (float*)sh_base;
    for (int p = blockIdx.x; p < NP; p += NBLK) {
        const int t0 = p << shift;
        for (int i = threadIdx.x; i < np; i += 256) { sh_h[i] = 0; lws[i] = 0.f; }
        __syncthreads();
        int n = tail[p];
        if (n > ecap) n = ecap;
        const u64* L = glist + (size_t)p * ecap;
        for (int j = threadIdx.x; j < n; j += 256) {
            u64 v = L[j];
            int t = (int)(v >> 32);
            int loc = t - t0;
            unsigned int k = atomicAdd(&sh_h[loc], 1u);  // LDS
            if ((int)k < cap) {
                EW[(size_t)t * cap + k] = (unsigned int)v;
                atomicAdd(&lws[loc], (float)((unsigned int)v & WQ_MASK));
            }
        }
        __syncthreads();
        for (int i = threadIdx.x; i < np; i += 256) {
            int t = t0 + i;
            if (t < N) {
                int c = (int)sh_h[i];
                c = (c < cap) ? c : cap;
                cnt[t] = c;
                dinv[t] = 1.0f / sqrtf(1.0f + lws[i] * (1.0f / WQ_SCALE));
            }
        }
        __syncthreads();
    }
}

// ---- gemm: H[N x BN] = dinv*(X @ W) fp16; 16row x 64col wave tiles ----
template <int BN, bool XFP32>
__device__ __forceinline__ void gemm_phase(const void* __restrict__ Xv,
                                           const __half* __restrict__ Wt,
                                           const float* __restrict__ dinv,
                                           __half* __restrict__ H, int N) {
    constexpr int NCH = BN / 64;  // col-half tasks per row-block
    const int lane = threadIdx.x & 63;
    const int wv = threadIdx.x >> 6;
    const int m = lane & 15;
    const int quad = lane >> 4;
    const int nrb = (N + 15) >> 4;
    const int total = nrb * NCH;
    for (int t = blockIdx.x * 4 + wv; t < total; t += NBLK * 4) {
        const int rb = (NCH == 2) ? (t >> 1) : t;
        const int ch = (NCH == 2) ? (t & 1) : 0;
        const int row = rb * 16 + m;
        const int rowc = (row < N) ? row : (N - 1);

        f16x8 xf[4];
        if constexpr (XFP32) {
            const float* X = (const float*)Xv;
#pragma unroll
            for (int s = 0; s < 4; s++) {
                const float4* p = (const float4*)(X + (size_t)rowc * 128 + s * 32 + quad * 8);
                float4 u0 = p[0], u1 = p[1];
                f16x8 f;
                f[0] = (_Float16)u0.x; f[1] = (_Float16)u0.y;
                f[2] = (_Float16)u0.z; f[3] = (_Float16)u0.w;
                f[4] = (_Float16)u1.x; f[5] = (_Float16)u1.y;
                f[6] = (_Float16)u1.z; f[7] = (_Float16)u1.w;
                xf[s] = f;
            }
        } else {
            const __half* X = (const __half*)Xv;
#pragma unroll
            for (int s = 0; s < 4; s++)
                xf[s] = *(const f16x8*)(X + (size_t)rowc * 128 + s * 32 + quad * 8);
        }

        f32x4 acc[4];
#pragma unroll
        for (int u = 0; u < 4; u++) acc[u] = (f32x4){0.f, 0.f, 0.f, 0.f};

#pragma unroll
        for (int s = 0; s < 4; s++) {
#pragma unroll
            for (int u = 0; u < 4; u++) {
                f16x8 wf = *(const f16x8*)(Wt + (size_t)(ch * 64 + u * 16 + m) * 128 + s * 32 + quad * 8);
                acc[u] = __builtin_amdgcn_mfma_f32_16x16x32_f16(wf, xf[s], acc[u], 0, 0, 0);
            }
        }

        if (row < N) {
            float sc = dinv[row];
#pragma unroll
            for (int u = 0; u < 4; u++) {
                __half2 h0 = __floats2half2_rn(sc * acc[u][0], sc * acc[u][1]);
                __half2 h1 = __floats2half2_rn(sc * acc[u][2], sc * acc[u][3]);
                __half2* dstp = (__half2*)(H + (size_t)row * BN + ch * 64 + u * 16 + quad * 4);
                dstp[0] = h0;
                dstp[1] = h1;
            }
        }
    }
}

// ---- agg: out = dinv*(sum w_e*Hs[src] + Hs[self]) + b; packed gathers ----
template <int DOUT, bool RELU>
__device__ __forceinline__ void agg_phase(const __half* __restrict__ H,
                                          const unsigned int* __restrict__ EW,
                                          const int* __restrict__ cnt,
                                          const float* __restrict__ dinv,
                                          const float* __restrict__ bias,
                                          void* __restrict__ Outv,
                                          int N, int cap) {
    const int lane = threadIdx.x & 63;
    const int ngrp = (N + 3) >> 2;
    for (int g = blockIdx.x; g < ngrp; g += NBLK) {
        int node = g * 4 + (int)(threadIdx.x >> 6);
        if (node >= N) continue;

        int c = cnt[node];
        c = (c < cap) ? c : cap;
        unsigned int meta = 0;
        if (lane < c) meta = EW[(size_t)node * cap + lane];
        float dt = dinv[node];

        if constexpr (DOUT == 128) {
            const int part = lane & 15;  // 16B chunk of the 256B row
            const int q = lane >> 4;     // edge within group of 4
            float acc[8];
#pragma unroll
            for (int j = 0; j < 8; j++) acc[j] = 0.f;

            int k = 0;
            for (; k + 16 <= c; k += 16) {
                f16x8 hv[4];
                float w[4];
#pragma unroll
                for (int gg = 0; gg < 4; gg++) {
                    unsigned int mm = SHFLU(meta, k + gg * 4 + q);
                    w[gg] = (float)(mm & WQ_MASK) * (1.0f / WQ_SCALE);
                    hv[gg] = *(const f16x8*)(H + (size_t)(mm >> WQ_BITS) * 128 + part * 8);
                }
#pragma unroll
                for (int gg = 0; gg < 4; gg++)
#pragma unroll
                    for (int j = 0; j < 8; j++)
                        acc[j] = fmaf(w[gg], (float)hv[gg][j], acc[j]);
            }
            for (; k < c; k += 4) {
                int idx = k + q;
                unsigned int mm = SHFLU(meta, (idx < c) ? idx : 0);
                float w = (idx < c) ? (float)(mm & WQ_MASK) * (1.0f / WQ_SCALE) : 0.f;
                unsigned int row = (idx < c) ? (mm >> WQ_BITS) : (unsigned int)node;
                f16x8 hv = *(const f16x8*)(H + (size_t)row * 128 + part * 8);
#pragma unroll
                for (int j = 0; j < 8; j++)
                    acc[j] = fmaf(w, (float)hv[j], acc[j]);
            }
#pragma unroll
            for (int j = 0; j < 8; j++) {
                acc[j] += __shfl_xor(acc[j], 16, 64);
                acc[j] += __shfl_xor(acc[j], 32, 64);
            }
            if (q == 0) {
                f16x8 sv = *(const f16x8*)(H + (size_t)node * 128 + part * 8);
                f32x4 b0v = *(const f32x4*)(bias + part * 8);
                f32x4 b1v = *(const f32x4*)(bias + part * 8 + 4);
                f16x8 ov;
#pragma unroll
                for (int j = 0; j < 8; j++) {
                    float bj = (j < 4) ? b0v[j] : b1v[j - 4];
                    float v = fmaf(dt, acc[j] + (float)sv[j], bj);
                    if (RELU) v = fmaxf(v, 0.f);
                    ov[j] = (_Float16)v;
                }
                *(f16x8*)((__half*)Outv + (size_t)node * 128 + part * 8) = ov;
            }
        } else {  // DOUT == 64, fp32 out; 128B rows -> 8 edges/instr
            const int part = lane & 7;
            const int q = lane >> 3;
            float acc[8];
#pragma unroll
            for (int j = 0; j < 8; j++) acc[j] = 0.f;

            int k = 0;
            for (; k + 32 <= c; k += 32) {
                f16x8 hv[4];
                float w[4];
#pragma unroll
                for (int gg = 0; gg < 4; gg++) {
                    unsigned int mm = SHFLU(meta, k + gg * 8 + q);
                    w[gg] = (float)(mm & WQ_MASK) * (1.0f / WQ_SCALE);
                    hv[gg] = *(const f16x8*)(H + (size_t)(mm >> WQ_BITS) * 64 + part * 8);
                }
#pragma unroll
                for (int gg = 0; gg < 4; gg++)
#pragma unroll
                    for (int j = 0; j < 8; j++)
                        acc[j] = fmaf(w[gg], (float)hv[gg][j], acc[j]);
            }
            for (; k < c; k += 8) {
                int idx = k + q;
                unsigned int mm = SHFLU(meta, (idx < c) ? idx : 0);
                float w = (idx < c) ? (float)(mm & WQ_MASK) * (1.0f / WQ_SCALE) : 0.f;
                unsigned int row = (idx < c) ? (mm >> WQ_BITS) : (unsigned int)node;
                f16x8 hv = *(const f16x8*)(H + (size_t)row * 64 + part * 8);
#pragma unroll
                for (int j = 0; j < 8; j++)
                    acc[j] = fmaf(w, (float)hv[j], acc[j]);
            }
#pragma unroll
            for (int j = 0; j < 8; j++) {
                acc[j] += __shfl_xor(acc[j], 8, 64);
                acc[j] += __shfl_xor(acc[j], 16, 64);
                acc[j] += __shfl_xor(acc[j], 32, 64);
            }
            if (q == 0) {
                f16x8 sv = *(const f16x8*)(H + (size_t)node * 64 + part * 8);
                f32x4 b0v = *(const f32x4*)(bias + part * 8);
                f32x4 b1v = *(const f32x4*)(bias + part * 8 + 4);
                f32x4 o0, o1;
#pragma unroll
                for (int j = 0; j < 8; j++) {
                    float bj = (j < 4) ? b0v[j] : b1v[j - 4];
                    float v = fmaf(dt, acc[j] + (float)sv[j], bj);
                    if (RELU) v = fmaxf(v, 0.f);
                    if (j < 4) o0[j] = v; else o1[j - 4] = v;
                }
                float* op = (float*)Outv + (size_t)node * 64 + part * 8;
                *(f32x4*)op = o0;
                *(f32x4*)(op + 4) = o1;
            }
        }
    }
}

// ---- the mega-kernel ----
__global__ __launch_bounds__(256, 8) void k_mega(
    const float* __restrict__ x, const int* __restrict__ src,
    const int* __restrict__ dst, const float* __restrict__ ew,
    const float* __restrict__ W0, const float* __restrict__ b0,
    const float* __restrict__ W1, const float* __restrict__ b1,
    const float* __restrict__ W2, const float* __restrict__ b2,
    int* cnt, float* dinv, unsigned int* EW, __half* bufH, __half* bufA,
    __half* wt0, __half* wt1, __half* wt2, int* tail,
    unsigned int* gcnt, unsigned int* root, unsigned int* gen,
    float* out, int N, int E, int cap, int NP, int shift, int ecap) {
    u64* glist = (u64*)bufH;  // aliased: dead until gemm0

    pre_phase(tail, NP, W0, W1, W2, wt0, wt1, wt2);
    gbar(gcnt, root, gen);
    bin_phase(src, dst, ew, tail, glist, E, ecap, NP, shift);
    gbar(gcnt, root, gen);
    fill_phase(tail, glist, ecap, cnt, dinv, EW, cap, N, NP, shift);
    gbar(gcnt, root, gen);

    gemm_phase<128, true>(x, wt0, dinv, bufH, N);
    gbar(gcnt, root, gen);
    agg_phase<128, true>(bufH, EW, cnt, dinv, b0, bufA, N, cap);
    gbar(gcnt, root, gen);

    gemm_phase<128, false>(bufA, wt1, dinv, bufH, N);
    gbar(gcnt, root, gen);
    agg_phase<128, true>(bufH, EW, cnt, dinv, b1, bufA, N, cap);
    gbar(gcnt, root, gen);

    gemm_phase<64, false>(bufA, wt2, dinv, bufH, N);
    gbar(gcnt, root, gen);
    agg_phase<64, false>(bufH, EW, cnt, dinv, b2, out, N, cap);
}

extern "C" void kernel_launch(void* const* d_in, const int* in_sizes, int n_in,
                              void* d_out, int out_size, void* d_ws, size_t ws_size,
                              hipStream_t stream) {
    const int N = in_sizes[0] / 128;   // x is [N,128]
    const int E = in_sizes[2];         // edge_weight is [E]

    const float* x  = (const float*)d_in[0];
    const int*   ei = (const int*)d_in[1];   // [2,E]: row0=src, row1=dst
    const int*   src = ei;
    const int*   dst = ei + E;
    const float* ew  = (const float*)d_in[2];
    const float* W0 = (const float*)d_in[3];
    const float* b0 = (const float*)d_in[4];
    const float* W1 = (const float*)d_in[5];
    const float* b1 = (const float*)d_in[6];
    const float* W2 = (const float*)d_in[7];
    const float* b2 = (const float*)d_in[8];

    // Partitioning: 64-node ranges; widen shift if N is huge so NP<=MAXNP.
    int shift = 6;
    while ((((N - 1) >> shift) + 1) > MAXNP) shift++;
    const int NP = ((N - 1) >> shift) + 1;

    // Workspace carve; bucket capacity adapts so we never write past d_ws.
    size_t fixed = (((size_t)N * 4 + 255) & ~(size_t)255)            // cnt
                 + (((size_t)N * 4 + 255) & ~(size_t)255)            // dinv
                 + 2 * (((size_t)N * 128 * 2 + 255) & ~(size_t)255)  // bufH, bufA fp16
                 + 3 * 33024                                         // wt0,wt1,wt2
                 + (((size_t)NP * 4 + 255) & ~(size_t)255)           // tail
                 + 16384 + 2048;                                     // barriers
    int cap = 64;
    if (ws_size > fixed) {
        size_t avail = (ws_size - fixed) / ((size_t)N * 4);
        if (avail < (size_t)cap) cap = (int)avail;
    } else {
        cap = 0;
    }

    char* p = (char*)d_ws;
    auto alloc = [&](size_t bytes) -> void* {
        void* r = (void*)p;
        p += (bytes + 255) & ~(size_t)255;
        return r;
    };
    int*          cnt  = (int*)alloc((size_t)N * 4);
    float*        dinv = (float*)alloc((size_t)N * 4);
    unsigned int* EW   = (unsigned int*)alloc((size_t)N * cap * 4);
    __half*       bufH = (__half*)alloc((size_t)N * 128 * 2);
    __half*       bufA = (__half*)alloc((size_t)N * 128 * 2);
    __half*       wt0  = (__half*)alloc(16384 * 2);
    __half*       wt1  = (__half*)alloc(16384 * 2);
    __half*       wt2  = (__half*)alloc(8192 * 2);
    int*          tail = (int*)alloc((size_t)NP * 4);
    unsigned int* bar  = (unsigned int*)alloc(16384);  // gcnt[64*32] + root + gen

    unsigned int* gcnt = bar;             // 64 entries, stride 32 u32 (8KB)
    unsigned int* root = bar + 64 * 32;
    unsigned int* gen  = bar + 64 * 32 + 32;

    // Phase-1 bin lists alias bufH (dead until gemm0): NP lists of ecap u64.
    int ecap = (int)(((size_t)N * 128 * 2) / ((size_t)NP * 8));  // ~2047 here

    // Zero barrier state (gen monotonic within a launch; reset per launch).
    hipMemsetAsync(bar, 0, 16384, stream);

    dim3 blk(256);
    dim3 grid(NBLK);  // 2048 = 256 CU x 8 blocks/CU, all co-resident
    k_mega<<<grid, blk, 0, stream>>>(x, src, dst, ew, W0, b0, W1, b1, W2, b2,
                                     cnt, dinv, EW, bufH, bufA, wt0, wt1, wt2,
                                     tail, gcnt, root, gen,
                                     (float*)d_out, N, E, cap, NP, shift, ecap);
}

// Round 11
// 1053.370 us; speedup vs baseline: 3.1932x; 3.1932x over previous
//
#include <hip/hip_runtime.h>
#include <hip/hip_fp16.h>

// GCN 3-layer encoder for MI355X — R11: mega-kernel with CACHE-SAFE barrier.
// R10 (3363us, 8x regression) root cause: ACQUIRE-scope polling loads lower
// to load+buffer_inv -> every poll iteration of ~1500 idle blocks invalidated
// all 8 XCD L2s while active blocks worked (VALUBusy 2.8%, FETCH +300MB).
// R11 barrier: RELAXED polls (agent atomics are L3-serviced -> visible, no
// invalidation), ONE fence(release,"agent") before arrival (wbl2; required
// for cross-XCD visibility of plain stores) and ONE fence(acquire,"agent")
// after wake. Per-barrier dedicated state (8 x {gcnt[64],root,flag}) -- no
// resets, no reset/wake races. s_sleep(16) poll pacing.
// Phases unchanged from R10 (math byte-identical to R9, 427us baseline):
// pre | bin | fill | [gemm -> agg] x3, 2048 blocks x 256 thr (8/CU).

typedef __attribute__((ext_vector_type(8))) _Float16 f16x8;
typedef __attribute__((ext_vector_type(4))) float f32x4;
typedef unsigned long long u64;

#define WQ_BITS 15
#define WQ_SCALE 32768.0f
#define WQ_MASK 32767u
#define MAXNP 2048
#define NBLK 2048
#define BINB 512
#define BARSTRIDE 768  // u32 per barrier: gcnt 64*8=512 | root@512 | flag@544

#define SHFLU(v, k) ((unsigned int)__shfl((int)(v), (k), 64))

__shared__ unsigned int sh_h[MAXNP];   // bin: histogram | fill: slot counters
__shared__ int sh_base[MAXNP];         // bin: bases     | fill: f32 weight sums

// Grid barrier, cache-safe. Two-level (64 groups x 32). Dedicated state per
// barrier index: no resets. RELAXED arrivals/polls; fences only at the edges.
__device__ __forceinline__ void gbar(unsigned int* bar, int bi) {
    __syncthreads();
    if (threadIdx.x == 0) {
        unsigned int* st = bar + bi * BARSTRIDE;
        unsigned int* gcnt = st;          // 64 entries, stride 8 u32
        unsigned int* root = st + 512;
        unsigned int* flag = st + 544;
        // make this block's phase writes visible at L3/HBM (wbl2)
        __builtin_amdgcn_fence(__ATOMIC_RELEASE, "agent");
        const int grp = (int)(blockIdx.x >> 5);
        unsigned int a = __hip_atomic_fetch_add(&gcnt[grp * 8], 1u,
                                                __ATOMIC_RELAXED,
                                                __HIP_MEMORY_SCOPE_AGENT);
        if (a == 31u) {
            unsigned int r = __hip_atomic_fetch_add(root, 1u, __ATOMIC_RELAXED,
                                                    __HIP_MEMORY_SCOPE_AGENT);
            if (r == 63u)
                __hip_atomic_store(flag, 1u, __ATOMIC_RELAXED,
                                   __HIP_MEMORY_SCOPE_AGENT);
        }
        while (__hip_atomic_load(flag, __ATOMIC_RELAXED,
                                 __HIP_MEMORY_SCOPE_AGENT) == 0u)
            __builtin_amdgcn_s_sleep(16);
        // drop stale local cache before reading other blocks' output
        __builtin_amdgcn_fence(__ATOMIC_ACQUIRE, "agent");
    }
    __syncthreads();
}

// ---- P0: zero tail + transpose W0/W1/W2 (fp32 [k][n]) -> f16 Wt [n][k] ----
__device__ __forceinline__ void pre_phase(int* tail, int NP,
                                          const float* __restrict__ W0,
                                          const float* __restrict__ W1,
                                          const float* __restrict__ W2,
                                          __half* __restrict__ wt0,
                                          __half* __restrict__ wt1,
                                          __half* __restrict__ wt2) {
    int preN = (NP > 40960) ? NP : 40960;
    for (int id = blockIdx.x * 256 + threadIdx.x; id < preN; id += NBLK * 256) {
        if (id < NP) tail[id] = 0;
        if (id < 16384) {
            int n = id >> 7, k = id & 127;
            wt0[id] = __float2half(W0[k * 128 + n]);
        } else if (id < 32768) {
            int j = id - 16384, n = j >> 7, k = j & 127;
            wt1[j] = __float2half(W1[k * 128 + n]);
        } else if (id < 40960) {
            int j = id - 32768, n = j >> 7, k = j & 127;  // n in [0,64)
            wt2[j] = __float2half(W2[k * 64 + n]);
        }
    }
}

// ---- P1: bin edges into NP per-node-range lists (blocks 0..BINB-1) ----
__device__ __forceinline__ void bin_phase(const int* __restrict__ src,
                                          const int* __restrict__ dst,
                                          const float* __restrict__ w,
                                          int* tail, u64* __restrict__ glist,
                                          int E, int ecap, int NP, int shift) {
    if (blockIdx.x >= BINB) return;  // falls through to the next barrier
    const int per = (E + BINB - 1) / BINB;
    const int e0 = blockIdx.x * per;
    const int e1 = (e0 + per < E) ? e0 + per : E;

    for (int i = threadIdx.x; i < NP; i += 256) sh_h[i] = 0;
    __syncthreads();
    for (int e = e0 + (int)threadIdx.x; e < e1; e += 256) {
        int p = dst[e] >> shift;
        atomicAdd(&sh_h[p], 1u);
    }
    __syncthreads();
    for (int i = threadIdx.x; i < NP; i += 256) {
        unsigned int c = sh_h[i];
        sh_base[i] = c ? atomicAdd(&tail[i], (int)c) : 0;
    }
    __syncthreads();
    for (int e = e0 + (int)threadIdx.x; e < e1; e += 256) {
        int t = dst[e];  // L2-hot (pass 1 cached it)
        int p = t >> shift;
        int s = __builtin_nontemporal_load(src + e);
        float we = __builtin_nontemporal_load(w + e);
        int wq = (int)(we * WQ_SCALE + 0.5f);
        wq = (wq < (int)WQ_MASK) ? wq : (int)WQ_MASK;
        u64 v = ((u64)(unsigned)t << 32) |
                ((unsigned)s << WQ_BITS) | (unsigned)wq;
        unsigned int idx = atomicSub(&sh_h[p], 1u) - 1u;  // LDS, order-free
        int pos = sh_base[p] + (int)idx;
        if (pos < ecap) glist[(size_t)p * ecap + pos] = v;
    }
}

// ---- P2: per-partition scatter; LDS slot counters; emits EW, cnt, dinv ----
__device__ __forceinline__ void fill_phase(const int* __restrict__ tail,
                                           const u64* __restrict__ glist,
                                           int ecap, int* __restrict__ cnt,
                                           float* __restrict__ dinv,
                                           unsigned int* __restrict__ EW,
                                           int cap, int N, int NP, int shift) {
    const int np = 1 << shift;
    float* lws = (float*)sh_base;
    for (int p = blockIdx.x; p < NP; p += NBLK) {
        const int t0 = p << shift;
        for (int i = threadIdx.x; i < np; i += 256) { sh_h[i] = 0; lws[i] = 0.f; }
        __syncthreads();
        int n = tail[p];
        if (n > ecap) n = ecap;
        const u64* L = glist + (size_t)p * ecap;
        for (int j = threadIdx.x; j < n; j += 256) {
            u64 v = L[j];
            int t = (int)(v >> 32);
            int loc = t - t0;
            unsigned int k = atomicAdd(&sh_h[loc], 1u);  // LDS
            if ((int)k < cap) {
                EW[(size_t)t * cap + k] = (unsigned int)v;
                atomicAdd(&lws[loc], (float)((unsigned int)v & WQ_MASK));
            }
        }
        __syncthreads();
        for (int i = threadIdx.x; i < np; i += 256) {
            int t = t0 + i;
            if (t < N) {
                int c = (int)sh_h[i];
                c = (c < cap) ? c : cap;
                cnt[t] = c;
                dinv[t] = 1.0f / sqrtf(1.0f + lws[i] * (1.0f / WQ_SCALE));
            }
        }
        __syncthreads();
    }
}

// ---- gemm: H[N x BN] = dinv*(X @ W) fp16; 16row x 64col wave tiles ----
template <int BN, bool XFP32>
__device__ __forceinline__ void gemm_phase(const void* __restrict__ Xv,
                                           const __half* __restrict__ Wt,
                                           const float* __restrict__ dinv,
                                           __half* __restrict__ H, int N) {
    constexpr int NCH = BN / 64;  // col-half tasks per row-block
    const int lane = threadIdx.x & 63;
    const int wv = threadIdx.x >> 6;
    const int m = lane & 15;
    const int quad = lane >> 4;
    const int nrb = (N + 15) >> 4;
    const int total = nrb * NCH;
    for (int t = blockIdx.x * 4 + wv; t < total; t += NBLK * 4) {
        const int rb = (NCH == 2) ? (t >> 1) : t;
        const int ch = (NCH == 2) ? (t & 1) : 0;
        const int row = rb * 16 + m;
        const int rowc = (row < N) ? row : (N - 1);

        f16x8 xf[4];
        if constexpr (XFP32) {
            const float* X = (const float*)Xv;
#pragma unroll
            for (int s = 0; s < 4; s++) {
                const float4* p = (const float4*)(X + (size_t)rowc * 128 + s * 32 + quad * 8);
                float4 u0 = p[0], u1 = p[1];
                f16x8 f;
                f[0] = (_Float16)u0.x; f[1] = (_Float16)u0.y;
                f[2] = (_Float16)u0.z; f[3] = (_Float16)u0.w;
                f[4] = (_Float16)u1.x; f[5] = (_Float16)u1.y;
                f[6] = (_Float16)u1.z; f[7] = (_Float16)u1.w;
                xf[s] = f;
            }
        } else {
            const __half* X = (const __half*)Xv;
#pragma unroll
            for (int s = 0; s < 4; s++)
                xf[s] = *(const f16x8*)(X + (size_t)rowc * 128 + s * 32 + quad * 8);
        }

        f32x4 acc[4];
#pragma unroll
        for (int u = 0; u < 4; u++) acc[u] = (f32x4){0.f, 0.f, 0.f, 0.f};

#pragma unroll
        for (int s = 0; s < 4; s++) {
#pragma unroll
            for (int u = 0; u < 4; u++) {
                f16x8 wf = *(const f16x8*)(Wt + (size_t)(ch * 64 + u * 16 + m) * 128 + s * 32 + quad * 8);
                acc[u] = __builtin_amdgcn_mfma_f32_16x16x32_f16(wf, xf[s], acc[u], 0, 0, 0);
            }
        }

        if (row < N) {
            float sc = dinv[row];
#pragma unroll
            for (int u = 0; u < 4; u++) {
                __half2 h0 = __floats2half2_rn(sc * acc[u][0], sc * acc[u][1]);
                __half2 h1 = __floats2half2_rn(sc * acc[u][2], sc * acc[u][3]);
                __half2* dstp = (__half2*)(H + (size_t)row * BN + ch * 64 + u * 16 + quad * 4);
                dstp[0] = h0;
                dstp[1] = h1;
            }
        }
    }
}

// ---- agg: out = dinv*(sum w_e*Hs[src] + Hs[self]) + b; packed gathers ----
template <int DOUT, bool RELU>
__device__ __forceinline__ void agg_phase(const __half* __restrict__ H,
                                          const unsigned int* __restrict__ EW,
                                          const int* __restrict__ cnt,
                                          const float* __restrict__ dinv,
                                          const float* __restrict__ bias,
                                          void* __restrict__ Outv,
                                          int N, int cap) {
    const int lane = threadIdx.x & 63;
    const int ngrp = (N + 3) >> 2;
    for (int g = blockIdx.x; g < ngrp; g += NBLK) {
        int node = g * 4 + (int)(threadIdx.x >> 6);
        if (node >= N) continue;

        int c = cnt[node];
        c = (c < cap) ? c : cap;
        unsigned int meta = 0;
        if (lane < c) meta = EW[(size_t)node * cap + lane];
        float dt = dinv[node];

        if constexpr (DOUT == 128) {
            const int part = lane & 15;  // 16B chunk of the 256B row
            const int q = lane >> 4;     // edge within group of 4
            float acc[8];
#pragma unroll
            for (int j = 0; j < 8; j++) acc[j] = 0.f;

            int k = 0;
            for (; k + 16 <= c; k += 16) {
                f16x8 hv[4];
                float w[4];
#pragma unroll
                for (int gg = 0; gg < 4; gg++) {
                    unsigned int mm = SHFLU(meta, k + gg * 4 + q);
                    w[gg] = (float)(mm & WQ_MASK) * (1.0f / WQ_SCALE);
                    hv[gg] = *(const f16x8*)(H + (size_t)(mm >> WQ_BITS) * 128 + part * 8);
                }
#pragma unroll
                for (int gg = 0; gg < 4; gg++)
#pragma unroll
                    for (int j = 0; j < 8; j++)
                        acc[j] = fmaf(w[gg], (float)hv[gg][j], acc[j]);
            }
            for (; k < c; k += 4) {
                int idx = k + q;
                unsigned int mm = SHFLU(meta, (idx < c) ? idx : 0);
                float w = (idx < c) ? (float)(mm & WQ_MASK) * (1.0f / WQ_SCALE) : 0.f;
                unsigned int row = (idx < c) ? (mm >> WQ_BITS) : (unsigned int)node;
                f16x8 hv = *(const f16x8*)(H + (size_t)row * 128 + part * 8);
#pragma unroll
                for (int j = 0; j < 8; j++)
                    acc[j] = fmaf(w, (float)hv[j], acc[j]);
            }
#pragma unroll
            for (int j = 0; j < 8; j++) {
                acc[j] += __shfl_xor(acc[j], 16, 64);
                acc[j] += __shfl_xor(acc[j], 32, 64);
            }
            if (q == 0) {
                f16x8 sv = *(const f16x8*)(H + (size_t)node * 128 + part * 8);
                f32x4 b0v = *(const f32x4*)(bias + part * 8);
                f32x4 b1v = *(const f32x4*)(bias + part * 8 + 4);
                f16x8 ov;
#pragma unroll
                for (int j = 0; j < 8; j++) {
                    float bj = (j < 4) ? b0v[j] : b1v[j - 4];
                    float v = fmaf(dt, acc[j] + (float)sv[j], bj);
                    if (RELU) v = fmaxf(v, 0.f);
                    ov[j] = (_Float16)v;
                }
                *(f16x8*)((__half*)Outv + (size_t)node * 128 + part * 8) = ov;
            }
        } else {  // DOUT == 64, fp32 out; 128B rows -> 8 edges/instr
            const int part = lane & 7;
            const int q = lane >> 3;
            float acc[8];
#pragma unroll
            for (int j = 0; j < 8; j++) acc[j] = 0.f;

            int k = 0;
            for (; k + 32 <= c; k += 32) {
                f16x8 hv[4];
                float w[4];
#pragma unroll
                for (int gg = 0; gg < 4; gg++) {
                    unsigned int mm = SHFLU(meta, k + gg * 8 + q);
                    w[gg] = (float)(mm & WQ_MASK) * (1.0f / WQ_SCALE);
                    hv[gg] = *(const f16x8*)(H + (size_t)(mm >> WQ_BITS) * 64 + part * 8);
                }
#pragma unroll
                for (int gg = 0; gg < 4; gg++)
#pragma unroll
                    for (int j = 0; j < 8; j++)
                        acc[j] = fmaf(w[gg], (float)hv[gg][j], acc[j]);
            }
            for (; k < c; k += 8) {
                int idx = k + q;
                unsigned int mm = SHFLU(meta, (idx < c) ? idx : 0);
                float w = (idx < c) ? (float)(mm & WQ_MASK) * (1.0f / WQ_SCALE) : 0.f;
                unsigned int row = (idx < c) ? (mm >> WQ_BITS) : (unsigned int)node;
                f16x8 hv = *(const f16x8*)(H + (size_t)row * 64 + part * 8);
#pragma unroll
                for (int j = 0; j < 8; j++)
                    acc[j] = fmaf(w, (float)hv[j], acc[j]);
            }
#pragma unroll
            for (int j = 0; j < 8; j++) {
                acc[j] += __shfl_xor(acc[j], 8, 64);
                acc[j] += __shfl_xor(acc[j], 16, 64);
                acc[j] += __shfl_xor(acc[j], 32, 64);
            }
            if (q == 0) {
                f16x8 sv = *(const f16x8*)(H + (size_t)node * 64 + part * 8);
                f32x4 b0v = *(const f32x4*)(bias + part * 8);
                f32x4 b1v = *(const f32x4*)(bias + part * 8 + 4);
                f32x4 o0, o1;
#pragma unroll
                for (int j = 0; j < 8; j++) {
                    float bj = (j < 4) ? b0v[j] : b1v[j - 4];
                    float v = fmaf(dt, acc[j] + (float)sv[j], bj);
                    if (RELU) v = fmaxf(v, 0.f);
                    if (j < 4) o0[j] = v; else o1[j - 4] = v;
                }
                float* op = (float*)Outv + (size_t)node * 64 + part * 8;
                *(f32x4*)op = o0;
                *(f32x4*)(op + 4) = o1;
            }
        }
    }
}

// ---- the mega-kernel ----
__global__ __launch_bounds__(256, 8) void k_mega(
    const float* __restrict__ x, const int* __restrict__ src,
    const int* __restrict__ dst, const float* __restrict__ ew,
    const float* __restrict__ W0, const float* __restrict__ b0,
    const float* __restrict__ W1, const float* __restrict__ b1,
    const float* __restrict__ W2, const float* __restrict__ b2,
    int* cnt, float* dinv, unsigned int* EW, __half* bufH, __half* bufA,
    __half* wt0, __half* wt1, __half* wt2, int* tail, unsigned int* bar,
    float* out, int N, int E, int cap, int NP, int shift, int ecap) {
    u64* glist = (u64*)bufH;  // aliased: dead until gemm0

    pre_phase(tail, NP, W0, W1, W2, wt0, wt1, wt2);
    gbar(bar, 0);
    bin_phase(src, dst, ew, tail, glist, E, ecap, NP, shift);
    gbar(bar, 1);
    fill_phase(tail, glist, ecap, cnt, dinv, EW, cap, N, NP, shift);
    gbar(bar, 2);

    gemm_phase<128, true>(x, wt0, dinv, bufH, N);
    gbar(bar, 3);
    agg_phase<128, true>(bufH, EW, cnt, dinv, b0, bufA, N, cap);
    gbar(bar, 4);

    gemm_phase<128, false>(bufA, wt1, dinv, bufH, N);
    gbar(bar, 5);
    agg_phase<128, true>(bufH, EW, cnt, dinv, b1, bufA, N, cap);
    gbar(bar, 6);

    gemm_phase<64, false>(bufA, wt2, dinv, bufH, N);
    gbar(bar, 7);
    agg_phase<64, false>(bufH, EW, cnt, dinv, b2, out, N, cap);
}

extern "C" void kernel_launch(void* const* d_in, const int* in_sizes, int n_in,
                              void* d_out, int out_size, void* d_ws, size_t ws_size,
                              hipStream_t stream) {
    const int N = in_sizes[0] / 128;   // x is [N,128]
    const int E = in_sizes[2];         // edge_weight is [E]

    const float* x  = (const float*)d_in[0];
    const int*   ei = (const int*)d_in[1];   // [2,E]: row0=src, row1=dst
    const int*   src = ei;
    const int*   dst = ei + E;
    const float* ew  = (const float*)d_in[2];
    const float* W0 = (const float*)d_in[3];
    const float* b0 = (const float*)d_in[4];
    const float* W1 = (const float*)d_in[5];
    const float* b1 = (const float*)d_in[6];
    const float* W2 = (const float*)d_in[7];
    const float* b2 = (const float*)d_in[8];

    // Partitioning: 64-node ranges; widen shift if N is huge so NP<=MAXNP.
    int shift = 6;
    while ((((N - 1) >> shift) + 1) > MAXNP) shift++;
    const int NP = ((N - 1) >> shift) + 1;

    // Workspace carve; bucket capacity adapts so we never write past d_ws.
    size_t fixed = (((size_t)N * 4 + 255) & ~(size_t)255)            // cnt
                 + (((size_t)N * 4 + 255) & ~(size_t)255)            // dinv
                 + 2 * (((size_t)N * 128 * 2 + 255) & ~(size_t)255)  // bufH, bufA fp16
                 + 3 * 33024                                         // wt0,wt1,wt2
                 + (((size_t)NP * 4 + 255) & ~(size_t)255)           // tail
                 + 32768 + 2048;                                     // barriers
    int cap = 64;
    if (ws_size > fixed) {
        size_t avail = (ws_size - fixed) / ((size_t)N * 4);
        if (avail < (size_t)cap) cap = (int)avail;
    } else {
        cap = 0;
    }

    char* p = (char*)d_ws;
    auto alloc = [&](size_t bytes) -> void* {
        void* r = (void*)p;
        p += (bytes + 255) & ~(size_t)255;
        return r;
    };
    int*          cnt  = (int*)alloc((size_t)N * 4);
    float*        dinv = (float*)alloc((size_t)N * 4);
    unsigned int* EW   = (unsigned int*)alloc((size_t)N * cap * 4);
    __half*       bufH = (__half*)alloc((size_t)N * 128 * 2);
    __half*       bufA = (__half*)alloc((size_t)N * 128 * 2);
    __half*       wt0  = (__half*)alloc(16384 * 2);
    __half*       wt1  = (__half*)alloc(16384 * 2);
    __half*       wt2  = (__half*)alloc(8192 * 2);
    int*          tail = (int*)alloc((size_t)NP * 4);
    unsigned int* bar  = (unsigned int*)alloc(32768);  // 8 x BARSTRIDE u32

    // Phase-1 bin lists alias bufH (dead until gemm0): NP lists of ecap u64.
    int ecap = (int)(((size_t)N * 128 * 2) / ((size_t)NP * 8));  // ~2047 here

    // Zero barrier state each launch (captured by graph; replayed per iter).
    hipMemsetAsync(bar, 0, 32768, stream);

    dim3 blk(256);
    dim3 grid(NBLK);  // 2048 = 256 CU x 8 blocks/CU, all co-resident
    k_mega<<<grid, blk, 0, stream>>>(x, src, dst, ew, W0, b0, W1, b1, W2, b2,
                                     cnt, dinv, EW, bufH, bufA, wt0, wt1, wt2,
                                     tail, bar,
                                     (float*)d_out, N, E, cap, NP, shift, ecap);
}

// Round 12
// 425.915 us; speedup vs baseline: 7.8973x; 2.4732x over previous
//
#include <hip/hip_runtime.h>
#include <hip/hip_fp16.h>

// GCN 3-layer encoder for MI355X — R12: R9 base (427us best) + barrier-free
// fill+gemm0 fusion. R10/R11 refuted in-kernel grid barriers (each release
// fence = 2048x buffer_wbl2 -> ~85us/barrier, FETCH+WRITE +600MB); R11 also
// showed launch gaps are small (mega-kernel 971us with ZERO gaps vs 427
// dispatched). The only barrier-FREE fusion: fill's per-partition dinv is
// exactly what gemm0 needs for its 64-row block -> block p fills partition p
// (LDS slot counters, R9-exact), stores dinv into freed LDS, syncs, runs the
// 64-row MFMA gemm with LDS dinv. glist moves to bufA (dead until agg0) so
// the fused block's bufH writes can't clobber unread neighbor lists.
// k_pre -> k_bin -> k_fillgemm0 -> agg0 -> [gemm -> agg] x2

typedef __attribute__((ext_vector_type(8))) _Float16 f16x8;
typedef __attribute__((ext_vector_type(4))) float f32x4;
typedef unsigned long long u64;

#define WQ_BITS 15
#define WQ_SCALE 32768.0f
#define WQ_MASK 32767u
#define MAXNP 2048

#define SHFLU(v, k) ((unsigned int)__shfl((int)(v), (k), 64))

// Fused: zero tails + transpose W0/W1/W2 (fp32 [k][n]) into f16 Wt [n][k].
__global__ __launch_bounds__(256) void k_pre(int* tail, int NP,
                                             const float* __restrict__ W0,
                                             const float* __restrict__ W1,
                                             const float* __restrict__ W2,
                                             __half* __restrict__ wt0,
                                             __half* __restrict__ wt1,
                                             __half* __restrict__ wt2) {
    int id = blockIdx.x * 256 + threadIdx.x;
    if (id < NP) tail[id] = 0;
    if (id < 16384) {
        int n = id >> 7, k = id & 127;
        wt0[id] = __float2half(W0[k * 128 + n]);
    } else if (id < 32768) {
        int j = id - 16384, n = j >> 7, k = j & 127;
        wt1[j] = __float2half(W1[k * 128 + n]);
    } else if (id < 40960) {
        int j = id - 32768, n = j >> 7, k = j & 127;  // n in [0,64)
        wt2[j] = __float2half(W2[k * 64 + n]);
    }
}

// Phase 1: bin edges into NP per-node-range lists. Two passes over a
// contiguous per-block chunk (2nd pass L2-hot). Global atomics: one per
// (block, nonzero partition) -- ~390K over 1563 spread words.
__global__ __launch_bounds__(256) void k_bin(const int* __restrict__ src,
                                             const int* __restrict__ dst,
                                             const float* __restrict__ w,
                                             int* tail, u64* __restrict__ glist,
                                             int E, int ecap, int NP, int shift) {
    __shared__ unsigned int h[MAXNP];
    __shared__ int base[MAXNP];
    const int nb = gridDim.x;
    const int per = (E + nb - 1) / nb;
    const int e0 = blockIdx.x * per;
    const int e1 = (e0 + per < E) ? e0 + per : E;

    for (int i = threadIdx.x; i < NP; i += 256) h[i] = 0;
    __syncthreads();
    for (int e = e0 + (int)threadIdx.x; e < e1; e += 256) {
        int p = dst[e] >> shift;
        atomicAdd(&h[p], 1u);
    }
    __syncthreads();
    for (int i = threadIdx.x; i < NP; i += 256) {
        unsigned int c = h[i];
        base[i] = c ? atomicAdd(&tail[i], (int)c) : 0;
    }
    __syncthreads();
    for (int e = e0 + (int)threadIdx.x; e < e1; e += 256) {
        int t = dst[e];  // L2-hot (pass 1 cached it)
        int p = t >> shift;
        int s = __builtin_nontemporal_load(src + e);
        float we = __builtin_nontemporal_load(w + e);
        int wq = (int)(we * WQ_SCALE + 0.5f);
        wq = (wq < (int)WQ_MASK) ? wq : (int)WQ_MASK;
        u64 v = ((u64)(unsigned)t << 32) |
                ((unsigned)s << WQ_BITS) | (unsigned)wq;
        unsigned int idx = atomicSub(&h[p], 1u) - 1u;  // LDS, order-free
        int pos = base[p] + (int)idx;
        if (pos < ecap) glist[(size_t)p * ecap + pos] = v;
    }
}

// Fused phase 2 + layer-0 GEMM. Block p: (a) fill partition p (64-node
// range): LDS slot counters, EW plain stores, cnt; dinv -> global AND the
// freed LDS float slot. (b) sync. (c) 64-row MFMA gemm (4 waves x 16 rows,
// NT=8) reading dinv from LDS -- no global dinv round-trip, no extra
// dispatch. glist lives in bufA; H written to bufH (disjoint buffers).
__global__ __launch_bounds__(256) void k_fillgemm0(
    const int* __restrict__ tail, const u64* __restrict__ glist, int ecap,
    int* __restrict__ cnt, float* __restrict__ dinv,
    unsigned int* __restrict__ EW, int cap, int N, int shift,
    const float* __restrict__ X, const __half* __restrict__ Wt,
    __half* __restrict__ H) {
    __shared__ unsigned int lcnt[MAXNP];
    __shared__ float lws[MAXNP];
    const int p = blockIdx.x;
    const int np = 1 << shift;
    const int t0 = p << shift;

    // ---- fill (R9-exact) ----
    for (int i = threadIdx.x; i < np; i += 256) { lcnt[i] = 0; lws[i] = 0.f; }
    __syncthreads();
    int n = tail[p];
    if (n > ecap) n = ecap;
    const u64* L = glist + (size_t)p * ecap;
    for (int j = threadIdx.x; j < n; j += 256) {
        u64 v = L[j];
        int t = (int)(v >> 32);
        int loc = t - t0;
        unsigned int k = atomicAdd(&lcnt[loc], 1u);  // LDS
        if ((int)k < cap) {
            EW[(size_t)t * cap + k] = (unsigned int)v;
            atomicAdd(&lws[loc], (float)((unsigned int)v & WQ_MASK));  // LDS f32
        }
    }
    __syncthreads();
    for (int i = threadIdx.x; i < np; i += 256) {
        int t = t0 + i;
        float dv = 1.0f / sqrtf(1.0f + lws[i] * (1.0f / WQ_SCALE));
        if (t < N) {
            int c = (int)lcnt[i];
            c = (c < cap) ? c : cap;
            cnt[t] = c;
            dinv[t] = dv;
        }
        lws[i] = dv;  // hand dinv to the gemm part via LDS
    }
    __syncthreads();

    // ---- layer-0 gemm for this partition's rows (X fp32 -> f16 cvt) ----
    const int lane = threadIdx.x & 63;
    const int wv = threadIdx.x >> 6;
    const int m = lane & 15;
    const int quad = lane >> 4;
    for (int rb = 0; rb < np; rb += 64) {
        const int rloc = rb + wv * 16 + m;
        const int row = t0 + rloc;
        const int rowc = (row < N) ? row : (N - 1);

        f16x8 xf[4];
#pragma unroll
        for (int s = 0; s < 4; s++) {
            const float4* pp = (const float4*)(X + (size_t)rowc * 128 + s * 32 + quad * 8);
            float4 u0 = pp[0], u1 = pp[1];
            f16x8 f;
            f[0] = (_Float16)u0.x; f[1] = (_Float16)u0.y;
            f[2] = (_Float16)u0.z; f[3] = (_Float16)u0.w;
            f[4] = (_Float16)u1.x; f[5] = (_Float16)u1.y;
            f[6] = (_Float16)u1.z; f[7] = (_Float16)u1.w;
            xf[s] = f;
        }

        f32x4 acc[8];
#pragma unroll
        for (int t = 0; t < 8; t++) acc[t] = (f32x4){0.f, 0.f, 0.f, 0.f};

#pragma unroll
        for (int s = 0; s < 4; s++) {
#pragma unroll
            for (int t = 0; t < 8; t++) {
                f16x8 wf = *(const f16x8*)(Wt + (size_t)(t * 16 + m) * 128 + s * 32 + quad * 8);
                acc[t] = __builtin_amdgcn_mfma_f32_16x16x32_f16(wf, xf[s], acc[t], 0, 0, 0);
            }
        }

        if (row < N) {
            float sc = lws[rloc];
#pragma unroll
            for (int t = 0; t < 8; t++) {
                __half2 h0 = __floats2half2_rn(sc * acc[t][0], sc * acc[t][1]);
                __half2 h1 = __floats2half2_rn(sc * acc[t][2], sc * acc[t][3]);
                __half2* dstp = (__half2*)(H + (size_t)row * 128 + t * 16 + quad * 4);
                dstp[0] = h0;
                dstp[1] = h1;
            }
        }
    }
}

// MFMA GEMM (layers 1,2): H[N x BN] = dinv[r]*(X[N x 128] @ W[128 x BN]).
template <int BN>
__global__ __launch_bounds__(256, 4) void k_gemm(const __half* __restrict__ X,
                                                 const __half* __restrict__ Wt,
                                                 const float* __restrict__ dinv,
                                                 __half* __restrict__ H, int N) {
    const int tid = threadIdx.x;
    const int lane = tid & 63;
    const int wv = tid >> 6;
    const int m = lane & 15;
    const int quad = lane >> 4;
    const int rb = blockIdx.x * 64;
    const int row = rb + wv * 16 + m;
    const int rowc = (row < N) ? row : (N - 1);

    f16x8 xf[4];
#pragma unroll
    for (int s = 0; s < 4; s++)
        xf[s] = *(const f16x8*)(X + (size_t)rowc * 128 + s * 32 + quad * 8);

    constexpr int NT = BN / 16;
    f32x4 acc[NT];
#pragma unroll
    for (int t = 0; t < NT; t++) acc[t] = (f32x4){0.f, 0.f, 0.f, 0.f};

#pragma unroll
    for (int s = 0; s < 4; s++) {
#pragma unroll
        for (int t = 0; t < NT; t++) {
            f16x8 wf = *(const f16x8*)(Wt + (size_t)(t * 16 + m) * 128 + s * 32 + quad * 8);
            acc[t] = __builtin_amdgcn_mfma_f32_16x16x32_f16(wf, xf[s], acc[t], 0, 0, 0);
        }
    }

    if (row < N) {
        float sc = dinv[row];
#pragma unroll
        for (int t = 0; t < NT; t++) {
            __half2 h0 = __floats2half2_rn(sc * acc[t][0], sc * acc[t][1]);
            __half2 h1 = __floats2half2_rn(sc * acc[t][2], sc * acc[t][3]);
            __half2* dstp = (__half2*)(H + (size_t)row * BN + t * 16 + quad * 4);
            dstp[0] = h0;
            dstp[1] = h1;
        }
    }
}

// Aggregate: out[t] = dinv[t] * (sum_e w_e * Hs[src_e] + Hs[t]) + b
// Wave per node, 4 nodes per 256-thr block. Packed gathers (R9):
// DOUT=128: 4 edges/instr (16 lanes x 16B = 256B row); DOUT=64: 8/instr.
template <int DOUT, bool RELU>
__global__ __launch_bounds__(256) void k_agg(const __half* __restrict__ H,
                                             const unsigned int* __restrict__ EW,
                                             const int* __restrict__ cnt,
                                             const float* __restrict__ dinv,
                                             const float* __restrict__ bias,
                                             void* __restrict__ Outv,
                                             int N, int cap) {
    int node = blockIdx.x * 4 + (threadIdx.x >> 6);
    if (node >= N) return;
    const int lane = threadIdx.x & 63;

    int c = cnt[node];  // wave-uniform
    c = (c < cap) ? c : cap;

    unsigned int meta = 0;
    if (lane < c) meta = EW[(size_t)node * cap + lane];

    float dt = dinv[node];

    if constexpr (DOUT == 128) {
        const int part = lane & 15;  // 16B chunk of the 256B row
        const int q = lane >> 4;     // edge within group of 4
        float acc[8];
#pragma unroll
        for (int j = 0; j < 8; j++) acc[j] = 0.f;

        int k = 0;
        for (; k + 16 <= c; k += 16) {
            f16x8 hv[4];
            float w[4];
#pragma unroll
            for (int g = 0; g < 4; g++) {
                unsigned int mm = SHFLU(meta, k + g * 4 + q);
                w[g] = (float)(mm & WQ_MASK) * (1.0f / WQ_SCALE);
                hv[g] = *(const f16x8*)(H + (size_t)(mm >> WQ_BITS) * 128 + part * 8);
            }
#pragma unroll
            for (int g = 0; g < 4; g++)
#pragma unroll
                for (int j = 0; j < 8; j++)
                    acc[j] = fmaf(w[g], (float)hv[g][j], acc[j]);
        }
        for (; k < c; k += 4) {
            int idx = k + q;
            unsigned int mm = SHFLU(meta, (idx < c) ? idx : 0);
            float w = (idx < c) ? (float)(mm & WQ_MASK) * (1.0f / WQ_SCALE) : 0.f;
            unsigned int row = (idx < c) ? (mm >> WQ_BITS) : (unsigned int)node;
            f16x8 hv = *(const f16x8*)(H + (size_t)row * 128 + part * 8);
#pragma unroll
            for (int j = 0; j < 8; j++)
                acc[j] = fmaf(w, (float)hv[j], acc[j]);
        }
#pragma unroll
        for (int j = 0; j < 8; j++) {
            acc[j] += __shfl_xor(acc[j], 16, 64);
            acc[j] += __shfl_xor(acc[j], 32, 64);
        }
        if (q == 0) {
            f16x8 sv = *(const f16x8*)(H + (size_t)node * 128 + part * 8);
            f32x4 b0v = *(const f32x4*)(bias + part * 8);
            f32x4 b1v = *(const f32x4*)(bias + part * 8 + 4);
            f16x8 ov;
#pragma unroll
            for (int j = 0; j < 8; j++) {
                float bj = (j < 4) ? b0v[j] : b1v[j - 4];
                float v = fmaf(dt, acc[j] + (float)sv[j], bj);
                if (RELU) v = fmaxf(v, 0.f);
                ov[j] = (_Float16)v;
            }
            *(f16x8*)((__half*)Outv + (size_t)node * 128 + part * 8) = ov;
        }
    } else {  // DOUT == 64, fp32 out; 128B rows -> 8 edges per instruction
        const int part = lane & 7;  // 16B chunk of the 128B row
        const int q = lane >> 3;    // edge within group of 8
        float acc[8];
#pragma unroll
        for (int j = 0; j < 8; j++) acc[j] = 0.f;

        int k = 0;
        for (; k + 32 <= c; k += 32) {
            f16x8 hv[4];
            float w[4];
#pragma unroll
            for (int g = 0; g < 4; g++) {
                unsigned int mm = SHFLU(meta, k + g * 8 + q);
                w[g] = (float)(mm & WQ_MASK) * (1.0f / WQ_SCALE);
                hv[g] = *(const f16x8*)(H + (size_t)(mm >> WQ_BITS) * 64 + part * 8);
            }
#pragma unroll
            for (int g = 0; g < 4; g++)
#pragma unroll
                for (int j = 0; j < 8; j++)
                    acc[j] = fmaf(w[g], (float)hv[g][j], acc[j]);
        }
        for (; k < c; k += 8) {
            int idx = k + q;
            unsigned int mm = SHFLU(meta, (idx < c) ? idx : 0);
            float w = (idx < c) ? (float)(mm & WQ_MASK) * (1.0f / WQ_SCALE) : 0.f;
            unsigned int row = (idx < c) ? (mm >> WQ_BITS) : (unsigned int)node;
            f16x8 hv = *(const f16x8*)(H + (size_t)row * 64 + part * 8);
#pragma unroll
            for (int j = 0; j < 8; j++)
                acc[j] = fmaf(w, (float)hv[j], acc[j]);
        }
#pragma unroll
        for (int j = 0; j < 8; j++) {
            acc[j] += __shfl_xor(acc[j], 8, 64);
            acc[j] += __shfl_xor(acc[j], 16, 64);
            acc[j] += __shfl_xor(acc[j], 32, 64);
        }
        if (q == 0) {
            f16x8 sv = *(const f16x8*)(H + (size_t)node * 64 + part * 8);
            f32x4 b0v = *(const f32x4*)(bias + part * 8);
            f32x4 b1v = *(const f32x4*)(bias + part * 8 + 4);
            f32x4 o0, o1;
#pragma unroll
            for (int j = 0; j < 8; j++) {
                float bj = (j < 4) ? b0v[j] : b1v[j - 4];
                float v = fmaf(dt, acc[j] + (float)sv[j], bj);
                if (RELU) v = fmaxf(v, 0.f);
                if (j < 4) o0[j] = v; else o1[j - 4] = v;
            }
            float* op = (float*)Outv + (size_t)node * 64 + part * 8;
            *(f32x4*)op = o0;
            *(f32x4*)(op + 4) = o1;
        }
    }
}

extern "C" void kernel_launch(void* const* d_in, const int* in_sizes, int n_in,
                              void* d_out, int out_size, void* d_ws, size_t ws_size,
                              hipStream_t stream) {
    const int N = in_sizes[0] / 128;   // x is [N,128]
    const int E = in_sizes[2];         // edge_weight is [E]

    const float* x  = (const float*)d_in[0];
    const int*   ei = (const int*)d_in[1];   // [2,E]: row0=src, row1=dst
    const int*   src = ei;
    const int*   dst = ei + E;
    const float* ew  = (const float*)d_in[2];
    const float* W0 = (const float*)d_in[3];
    const float* b0 = (const float*)d_in[4];
    const float* W1 = (const float*)d_in[5];
    const float* b1 = (const float*)d_in[6];
    const float* W2 = (const float*)d_in[7];
    const float* b2 = (const float*)d_in[8];

    // Partitioning: 64-node ranges; widen shift if N is huge so NP<=MAXNP.
    int shift = 6;
    while ((((N - 1) >> shift) + 1) > MAXNP) shift++;
    const int NP = ((N - 1) >> shift) + 1;

    // Workspace carve; bucket capacity adapts so we never write past d_ws.
    size_t fixed = (((size_t)N * 4 + 255) & ~(size_t)255)            // cnt
                 + (((size_t)N * 4 + 255) & ~(size_t)255)            // dinv
                 + 2 * (((size_t)N * 128 * 2 + 255) & ~(size_t)255)  // bufH, bufA fp16
                 + 3 * 33024                                         // wt0,wt1,wt2
                 + (((size_t)NP * 4 + 255) & ~(size_t)255)           // tail
                 + 2048;
    int cap = 64;
    if (ws_size > fixed) {
        size_t avail = (ws_size - fixed) / ((size_t)N * 4);
        if (avail < (size_t)cap) cap = (int)avail;
    } else {
        cap = 0;
    }

    char* p = (char*)d_ws;
    auto alloc = [&](size_t bytes) -> void* {
        void* r = (void*)p;
        p += (bytes + 255) & ~(size_t)255;
        return r;
    };
    int*          cnt  = (int*)alloc((size_t)N * 4);
    float*        dinv = (float*)alloc((size_t)N * 4);
    unsigned int* EW   = (unsigned int*)alloc((size_t)N * cap * 4);
    __half*       bufH = (__half*)alloc((size_t)N * 128 * 2);
    __half*       bufA = (__half*)alloc((size_t)N * 128 * 2);
    __half*       wt0  = (__half*)alloc(16384 * 2);
    __half*       wt1  = (__half*)alloc(16384 * 2);
    __half*       wt2  = (__half*)alloc(8192 * 2);
    int*          tail = (int*)alloc((size_t)NP * 4);

    // Bin lists alias bufA (dead until agg0 writes it): NP lists of ecap u64.
    // (bufH can't host them: fused fill+gemm0 writes H rows that would
    //  overlap neighboring partitions' unread lists.)
    u64* glist = (u64*)bufA;
    int  ecap  = (int)(((size_t)N * 128 * 2) / ((size_t)NP * 8));  // ~2047 here

    dim3 blk(256);
    int preN = (NP > 40960) ? NP : 40960;
    dim3 gPre((preN + 255) / 256);
    dim3 gBin(256);    // 1 block/CU; contiguous chunks, 2-pass (L2-hot)
    dim3 gFill(NP);    // 1 block per 64-node partition (fill + gemm0 fused)
    dim3 gGemm((N + 63) / 64);
    dim3 gWave((N + 3) / 4);

    k_pre<<<gPre, blk, 0, stream>>>(tail, NP, W0, W1, W2, wt0, wt1, wt2);
    k_bin<<<gBin, blk, 0, stream>>>(src, dst, ew, tail, glist, E, ecap, NP, shift);

    // layer 0: fill + gemm fused (dinv via LDS); then aggregate
    k_fillgemm0<<<gFill, blk, 0, stream>>>(tail, glist, ecap, cnt, dinv, EW,
                                           cap, N, shift, x, wt0, bufH);
    k_agg<128, true><<<gWave, blk, 0, stream>>>(bufH, EW, cnt, dinv, b0, bufA, N, cap);

    // layer 1
    k_gemm<128><<<gGemm, blk, 0, stream>>>(bufA, wt1, dinv, bufH, N);
    k_agg<128, true><<<gWave, blk, 0, stream>>>(bufH, EW, cnt, dinv, b1, bufA, N, cap);

    // layer 2 (no relu, fp32 out)
    k_gemm<64><<<gGemm, blk, 0, stream>>>(bufA, wt2, dinv, bufH, N);
    k_agg<64, false><<<gWave, blk, 0, stream>>>(bufH, EW, cnt, dinv, b2,
                                                d_out, N, cap);
}

// Round 13
// 410.734 us; speedup vs baseline: 8.1892x; 1.0370x over previous
//
#include <hip/hip_runtime.h>
#include <hip/hip_fp16.h>

// GCN 3-layer encoder for MI355X — R13: GEMM folded INTO the aggregate via
// associativity: out = S·(A·W)+b = (S·A)·W+b. Per layer, one kernel:
// block = 16 nodes; 4 waves gather T[16][128] = sum_e w_e*As[src]+As[self]
// (R9 packed-gather engine, byte-identical traffic) into LDS (stride 136
// halfs: 16B-aligned, breaks the 128B bank period), then run the proven
// k_gemm MFMA verbatim (A:=Wt-frag, B:=T-frag from LDS) with fused epilogue
// dt*U+b -> relu -> x dinv -> fp16 As_next (or fp32 final out). Deletes
// gemm1/gemm2 dispatches + their 51MB/layer H round-trip; fill drops its
// gemm0 work to As0 = dinv*x. 8 -> 6 dispatches.
// Build: two-phase (R4), glist aliases bufA (dead after fill; L0 writes it).
// All packed-word shifts unsigned (R7: readlane/shfl return SIGNED).
// k_pre -> k_bin -> k_fill(+As0) -> k_layer<W0> -> k_layer<W1> -> k_layer<W2>

typedef __attribute__((ext_vector_type(8))) _Float16 f16x8;
typedef __attribute__((ext_vector_type(4))) float f32x4;
typedef unsigned long long u64;

#define WQ_BITS 15
#define WQ_SCALE 32768.0f
#define WQ_MASK 32767u
#define MAXNP 2048
#define TSTR 136  // LDS T row stride in halfs (272B: 16B-aligned, non-pow2)

#define SHFLU(v, k) ((unsigned int)__shfl((int)(v), (k), 64))

// Fused: zero tails + transpose W0/W1/W2 (fp32 [k][n]) into f16 Wt [n][k].
__global__ __launch_bounds__(256) void k_pre(int* tail, int NP,
                                             const float* __restrict__ W0,
                                             const float* __restrict__ W1,
                                             const float* __restrict__ W2,
                                             __half* __restrict__ wt0,
                                             __half* __restrict__ wt1,
                                             __half* __restrict__ wt2) {
    int id = blockIdx.x * 256 + threadIdx.x;
    if (id < NP) tail[id] = 0;
    if (id < 16384) {
        int n = id >> 7, k = id & 127;
        wt0[id] = __float2half(W0[k * 128 + n]);
    } else if (id < 32768) {
        int j = id - 16384, n = j >> 7, k = j & 127;
        wt1[j] = __float2half(W1[k * 128 + n]);
    } else if (id < 40960) {
        int j = id - 32768, n = j >> 7, k = j & 127;  // n in [0,64)
        wt2[j] = __float2half(W2[k * 64 + n]);
    }
}

// Phase 1: bin edges into NP per-node-range lists. Two passes over a
// contiguous per-block chunk (2nd pass L2-hot). Global atomics: one per
// (block, nonzero partition) -- ~390K over 1563 spread words.
__global__ __launch_bounds__(256) void k_bin(const int* __restrict__ src,
                                             const int* __restrict__ dst,
                                             const float* __restrict__ w,
                                             int* tail, u64* __restrict__ glist,
                                             int E, int ecap, int NP, int shift) {
    __shared__ unsigned int h[MAXNP];
    __shared__ int base[MAXNP];
    const int nb = gridDim.x;
    const int per = (E + nb - 1) / nb;
    const int e0 = blockIdx.x * per;
    const int e1 = (e0 + per < E) ? e0 + per : E;

    for (int i = threadIdx.x; i < NP; i += 256) h[i] = 0;
    __syncthreads();
    for (int e = e0 + (int)threadIdx.x; e < e1; e += 256) {
        int p = dst[e] >> shift;
        atomicAdd(&h[p], 1u);
    }
    __syncthreads();
    for (int i = threadIdx.x; i < NP; i += 256) {
        unsigned int c = h[i];
        base[i] = c ? atomicAdd(&tail[i], (int)c) : 0;
    }
    __syncthreads();
    for (int e = e0 + (int)threadIdx.x; e < e1; e += 256) {
        int t = dst[e];  // L2-hot (pass 1 cached it)
        int p = t >> shift;
        int s = __builtin_nontemporal_load(src + e);
        float we = __builtin_nontemporal_load(w + e);
        int wq = (int)(we * WQ_SCALE + 0.5f);
        wq = (wq < (int)WQ_MASK) ? wq : (int)WQ_MASK;
        u64 v = ((u64)(unsigned)t << 32) |
                ((unsigned)s << WQ_BITS) | (unsigned)wq;
        unsigned int idx = atomicSub(&h[p], 1u) - 1u;  // LDS, order-free
        int pos = base[p] + (int)idx;
        if (pos < ecap) glist[(size_t)p * ecap + pos] = v;
    }
}

// Phase 2: one block per 64-node partition. LDS slot counters; EW plain
// stores; cnt + dinv; then As0 = dinv * x as fp16 (the layer-0 prescaled
// input -- replaces the old fused gemm0 entirely).
__global__ __launch_bounds__(256) void k_fill(const int* __restrict__ tail,
                                              const u64* __restrict__ glist,
                                              int ecap, int* __restrict__ cnt,
                                              float* __restrict__ dinv,
                                              unsigned int* __restrict__ EW,
                                              int cap, int N, int shift,
                                              const float* __restrict__ X,
                                              __half* __restrict__ As0) {
    __shared__ unsigned int lcnt[MAXNP];
    __shared__ float lws[MAXNP];
    const int p = blockIdx.x;
    const int np = 1 << shift;
    const int t0 = p << shift;

    for (int i = threadIdx.x; i < np; i += 256) { lcnt[i] = 0; lws[i] = 0.f; }
    __syncthreads();
    int n = tail[p];
    if (n > ecap) n = ecap;
    const u64* L = glist + (size_t)p * ecap;
    for (int j = threadIdx.x; j < n; j += 256) {
        u64 v = L[j];
        int t = (int)(v >> 32);
        int loc = t - t0;
        unsigned int k = atomicAdd(&lcnt[loc], 1u);  // LDS
        if ((int)k < cap) {
            EW[(size_t)t * cap + k] = (unsigned int)v;
            atomicAdd(&lws[loc], (float)((unsigned int)v & WQ_MASK));  // LDS f32
        }
    }
    __syncthreads();
    for (int i = threadIdx.x; i < np; i += 256) {
        int t = t0 + i;
        float dv = 1.0f / sqrtf(1.0f + lws[i] * (1.0f / WQ_SCALE));
        if (t < N) {
            int c = (int)lcnt[i];
            c = (c < cap) ? c : cap;
            cnt[t] = c;
            dinv[t] = dv;
        }
        lws[i] = dv;  // hand dinv to the As0 stage via LDS
    }
    __syncthreads();

    // As0 = dinv * x (fp32 -> fp16), 4 threads per row, 32 cols each.
    for (int rb = 0; rb < np; rb += 64) {
        int rloc = rb + (int)(threadIdx.x >> 2);
        int sub = threadIdx.x & 3;
        int r = t0 + rloc;
        if (rloc < np && r < N) {
            float dv = lws[rloc];
#pragma unroll
            for (int cc = 0; cc < 4; cc++) {
                int c0 = sub * 32 + cc * 8;
                float4 u0 = *(const float4*)(X + (size_t)r * 128 + c0);
                float4 u1 = *(const float4*)(X + (size_t)r * 128 + c0 + 4);
                f16x8 f;
                f[0] = (_Float16)(dv * u0.x); f[1] = (_Float16)(dv * u0.y);
                f[2] = (_Float16)(dv * u0.z); f[3] = (_Float16)(dv * u0.w);
                f[4] = (_Float16)(dv * u1.x); f[5] = (_Float16)(dv * u1.y);
                f[6] = (_Float16)(dv * u1.z); f[7] = (_Float16)(dv * u1.w);
                *(f16x8*)(As0 + (size_t)r * 128 + c0) = f;
            }
        }
    }
}

// Fused layer: block = 16 nodes. Phase A: 4 waves gather T rows (R9 packed
// gather: 4 edges per dwordx4 instruction) into LDS. Phase B: MFMA U = T@W
// (k_gemm-verbatim fragment indexing; waves split columns) with fused
// epilogue: v = dt*U + b; [relu]; store fp16 dt*v (As_next) or fp32 v (out).
template <int BNO, bool RELU, bool FINAL>
__global__ __launch_bounds__(256) void k_layer(const __half* __restrict__ As,
                                               const unsigned int* __restrict__ EW,
                                               const int* __restrict__ cnt,
                                               const float* __restrict__ dinv,
                                               const __half* __restrict__ Wt,
                                               const float* __restrict__ bias,
                                               void* __restrict__ Outv,
                                               int N, int cap) {
    __shared__ __align__(16) __half T[16][TSTR];
    const int tid = threadIdx.x;
    const int lane = tid & 63;
    const int wv = tid >> 6;
    const int base = blockIdx.x * 16;

    // zero T (OOB rows must be 0 for the MFMA phase)
    for (int i = tid; i < 16 * TSTR; i += 256) ((__half*)T)[i] = (__half)0.f;
    __syncthreads();

    // ---- Phase A: gather. Wave wv owns nodes base + wv*4 + {0..3}. ----
    const int part = lane & 15;  // 16B chunk of the 256B row
    const int q = lane >> 4;     // edge within group of 4
    for (int i = 0; i < 4; i++) {
        const int rloc = wv * 4 + i;
        const int node = base + rloc;
        if (node < N) {
            int c = cnt[node];
            c = (c < cap) ? c : cap;
            unsigned int meta = 0;
            if (lane < c) meta = EW[(size_t)node * cap + lane];

            float acc[8];
#pragma unroll
            for (int j = 0; j < 8; j++) acc[j] = 0.f;

            int k = 0;
            for (; k + 16 <= c; k += 16) {
                f16x8 hv[4];
                float w[4];
#pragma unroll
                for (int g = 0; g < 4; g++) {
                    unsigned int mm = SHFLU(meta, k + g * 4 + q);
                    w[g] = (float)(mm & WQ_MASK) * (1.0f / WQ_SCALE);
                    hv[g] = *(const f16x8*)(As + (size_t)(mm >> WQ_BITS) * 128 + part * 8);
                }
#pragma unroll
                for (int g = 0; g < 4; g++)
#pragma unroll
                    for (int j = 0; j < 8; j++)
                        acc[j] = fmaf(w[g], (float)hv[g][j], acc[j]);
            }
            for (; k < c; k += 4) {
                int idx = k + q;
                unsigned int mm = SHFLU(meta, (idx < c) ? idx : 0);
                float w = (idx < c) ? (float)(mm & WQ_MASK) * (1.0f / WQ_SCALE) : 0.f;
                unsigned int row = (idx < c) ? (mm >> WQ_BITS) : (unsigned int)node;
                f16x8 hv = *(const f16x8*)(As + (size_t)row * 128 + part * 8);
#pragma unroll
                for (int j = 0; j < 8; j++)
                    acc[j] = fmaf(w, (float)hv[j], acc[j]);
            }
#pragma unroll
            for (int j = 0; j < 8; j++) {
                acc[j] += __shfl_xor(acc[j], 16, 64);
                acc[j] += __shfl_xor(acc[j], 32, 64);
            }
            if (q == 0) {
                f16x8 sv = *(const f16x8*)(As + (size_t)node * 128 + part * 8);
                f16x8 tv;
#pragma unroll
                for (int j = 0; j < 8; j++)
                    tv[j] = (_Float16)(acc[j] + (float)sv[j]);
                *(f16x8*)&T[rloc][part * 8] = tv;
            }
        }
    }
    __syncthreads();

    // ---- Phase B: U = T @ W via MFMA (k_gemm-verbatim indexing). ----
    const int m = lane & 15;
    const int quad = lane >> 4;
    constexpr int NT = (BNO == 128) ? 2 : 1;  // col-tiles per wave (x4 waves)

    f16x8 xf[4];
#pragma unroll
    for (int s = 0; s < 4; s++)
        xf[s] = *(const f16x8*)&T[m][s * 32 + quad * 8];

    f32x4 acc[NT];
#pragma unroll
    for (int t = 0; t < NT; t++) acc[t] = (f32x4){0.f, 0.f, 0.f, 0.f};

#pragma unroll
    for (int s = 0; s < 4; s++) {
#pragma unroll
        for (int t = 0; t < NT; t++) {
            const int ct = wv * NT + t;
            f16x8 wf = *(const f16x8*)(Wt + (size_t)(ct * 16 + m) * 128 + s * 32 + quad * 8);
            acc[t] = __builtin_amdgcn_mfma_f32_16x16x32_f16(wf, xf[s], acc[t], 0, 0, 0);
        }
    }

    const int row = base + m;
    if (row < N) {
        float dt = dinv[row];
#pragma unroll
        for (int t = 0; t < NT; t++) {
            const int ct = wv * NT + t;
            const int col0 = ct * 16 + quad * 4;
            f32x4 bv = *(const f32x4*)(bias + col0);
            float v0 = fmaf(dt, acc[t][0], bv[0]);
            float v1 = fmaf(dt, acc[t][1], bv[1]);
            float v2 = fmaf(dt, acc[t][2], bv[2]);
            float v3 = fmaf(dt, acc[t][3], bv[3]);
            if (RELU) {
                v0 = fmaxf(v0, 0.f); v1 = fmaxf(v1, 0.f);
                v2 = fmaxf(v2, 0.f); v3 = fmaxf(v3, 0.f);
            }
            if constexpr (!FINAL) {
                // store As_next = dt * relu(v) as fp16
                __half2 h0 = __floats2half2_rn(dt * v0, dt * v1);
                __half2 h1 = __floats2half2_rn(dt * v2, dt * v3);
                __half2* dstp = (__half2*)((__half*)Outv + (size_t)row * 128 + col0);
                dstp[0] = h0;
                dstp[1] = h1;
            } else {
                f32x4 o;
                o[0] = v0; o[1] = v1; o[2] = v2; o[3] = v3;
                *(f32x4*)((float*)Outv + (size_t)row * 64 + col0) = o;
            }
        }
    }
}

extern "C" void kernel_launch(void* const* d_in, const int* in_sizes, int n_in,
                              void* d_out, int out_size, void* d_ws, size_t ws_size,
                              hipStream_t stream) {
    const int N = in_sizes[0] / 128;   // x is [N,128]
    const int E = in_sizes[2];         // edge_weight is [E]

    const float* x  = (const float*)d_in[0];
    const int*   ei = (const int*)d_in[1];   // [2,E]: row0=src, row1=dst
    const int*   src = ei;
    const int*   dst = ei + E;
    const float* ew  = (const float*)d_in[2];
    const float* W0 = (const float*)d_in[3];
    const float* b0 = (const float*)d_in[4];
    const float* W1 = (const float*)d_in[5];
    const float* b1 = (const float*)d_in[6];
    const float* W2 = (const float*)d_in[7];
    const float* b2 = (const float*)d_in[8];

    // Partitioning: 64-node ranges; widen shift if N is huge so NP<=MAXNP.
    int shift = 6;
    while ((((N - 1) >> shift) + 1) > MAXNP) shift++;
    const int NP = ((N - 1) >> shift) + 1;

    // Workspace carve; bucket capacity adapts so we never write past d_ws.
    size_t fixed = (((size_t)N * 4 + 255) & ~(size_t)255)            // cnt
                 + (((size_t)N * 4 + 255) & ~(size_t)255)            // dinv
                 + 2 * (((size_t)N * 128 * 2 + 255) & ~(size_t)255)  // bufH, bufA fp16
                 + 3 * 33024                                         // wt0,wt1,wt2
                 + (((size_t)NP * 4 + 255) & ~(size_t)255)           // tail
                 + 2048;
    int cap = 64;
    if (ws_size > fixed) {
        size_t avail = (ws_size - fixed) / ((size_t)N * 4);
        if (avail < (size_t)cap) cap = (int)avail;
    } else {
        cap = 0;
    }

    char* p = (char*)d_ws;
    auto alloc = [&](size_t bytes) -> void* {
        void* r = (void*)p;
        p += (bytes + 255) & ~(size_t)255;
        return r;
    };
    int*          cnt  = (int*)alloc((size_t)N * 4);
    float*        dinv = (float*)alloc((size_t)N * 4);
    unsigned int* EW   = (unsigned int*)alloc((size_t)N * cap * 4);
    __half*       bufH = (__half*)alloc((size_t)N * 128 * 2);
    __half*       bufA = (__half*)alloc((size_t)N * 128 * 2);
    __half*       wt0  = (__half*)alloc(16384 * 2);
    __half*       wt1  = (__half*)alloc(16384 * 2);
    __half*       wt2  = (__half*)alloc(8192 * 2);
    int*          tail = (int*)alloc((size_t)NP * 4);

    // Bin lists alias bufA (dead after k_fill; layer-0 writes bufA).
    u64* glist = (u64*)bufA;
    int  ecap  = (int)(((size_t)N * 128 * 2) / ((size_t)NP * 8));  // ~2047 here

    dim3 blk(256);
    int preN = (NP > 40960) ? NP : 40960;
    dim3 gPre((preN + 255) / 256);
    dim3 gBin(256);              // 1 block/CU; contiguous chunks, 2-pass
    dim3 gFill(NP);              // 1 block per 64-node partition
    dim3 gLayer((N + 15) / 16);  // 1 block per 16-node MFMA tile

    k_pre<<<gPre, blk, 0, stream>>>(tail, NP, W0, W1, W2, wt0, wt1, wt2);
    k_bin<<<gBin, blk, 0, stream>>>(src, dst, ew, tail, glist, E, ecap, NP, shift);
    k_fill<<<gFill, blk, 0, stream>>>(tail, glist, ecap, cnt, dinv, EW, cap, N,
                                      shift, x, bufH);

    // layer 0: gather(As0=bufH) -> @W0 -> As1=bufA
    k_layer<128, true, false><<<gLayer, blk, 0, stream>>>(bufH, EW, cnt, dinv,
                                                          wt0, b0, bufA, N, cap);
    // layer 1: gather(bufA) -> @W1 -> As2=bufH
    k_layer<128, true, false><<<gLayer, blk, 0, stream>>>(bufA, EW, cnt, dinv,
                                                          wt1, b1, bufH, N, cap);
    // layer 2: gather(bufH) -> @W2 -> out fp32 (no relu)
    k_layer<64, false, true><<<gLayer, blk, 0, stream>>>(bufH, EW, cnt, dinv,
                                                         wt2, b2, d_out, N, cap);
}